// Round 1
// baseline (666.400 us; speedup 1.0000x reference)
//
#include <hip/hip_runtime.h>
#include <hip/hip_bf16.h>

#define N_NODES 50000
#define E_EDGES 800000
#define NHEAD 4
#define DHEAD 32
#define DOUT 128   // NHEAD*DHEAD == D_IN
#define NEG_SLOPE 0.01f
#define EPS_F 1e-16f

// ---- monotone float<->uint encoding for atomicMax-based segment_max ----
__device__ __forceinline__ unsigned fenc(float f) {
    unsigned u = __float_as_uint(f);
    return (u & 0x80000000u) ? ~u : (u | 0x80000000u);
}
__device__ __forceinline__ float fdec(unsigned k) {
    unsigned u = (k & 0x80000000u) ? (k ^ 0x80000000u) : ~k;
    return __uint_as_float(u);
}

// ---- edge index fetch, robust to int32 vs int64 storage ----
// If edge_index is int64 (little-endian, values < 2^31), the int32 view is
// [lo0, 0, lo1, 0, ...]. Flag==1 means int64 layout.
__device__ __forceinline__ void load_edge(const int* __restrict__ ei, int isI64,
                                          int e, int& src, int& dst) {
    if (isI64) { src = ei[2 * e]; dst = ei[2 * (E_EDGES + e)]; }
    else       { src = ei[e];     dst = ei[E_EDGES + e]; }
}

// Detect int64-vs-int32: sample 2048 odd int32 positions; all zero => int64.
__global__ void k_detect(const int* __restrict__ ei, int* __restrict__ flag) {
    __shared__ int cnt;
    if (threadIdx.x == 0) cnt = 0;
    __syncthreads();
    int nz = 0;
    #pragma unroll
    for (int k = 0; k < 8; ++k) {
        int pos = (threadIdx.x + k * 256) * 2 + 1;   // < 4096, in-bounds either way
        if (ei[pos] != 0) nz = 1;
    }
    if (nz) atomicOr(&cnt, 1);
    __syncthreads();
    if (threadIdx.x == 0) *flag = (cnt == 0) ? 1 : 0;
}

// ---- K1: fused GEMM: h = x@W_proj, out(skip) = x@W_skip ----
// 8 nodes per block, 256 threads: thread j owns column j of [W_proj|W_skip].
// x reads are block-uniform -> scalar loads; W reads coalesced.
__global__ __launch_bounds__(256) void k_gemm(const float* __restrict__ x,
                                              const float* __restrict__ Wp,
                                              const float* __restrict__ Ws,
                                              float* __restrict__ h,
                                              float* __restrict__ out) {
    const int j = threadIdx.x;             // 0..255 over [W_proj | W_skip] cols
    const int nb = blockIdx.x * 8;         // 6250*8 == 50000 exactly
    const float* __restrict__ W = (j < DOUT) ? Wp : Ws;
    const int jj = j & (DOUT - 1);
    const float* __restrict__ xr = x + (size_t)nb * DOUT;

    float acc[8];
    #pragma unroll
    for (int i = 0; i < 8; ++i) acc[i] = 0.0f;

    #pragma unroll 4
    for (int k = 0; k < DOUT; ++k) {
        float w = W[k * DOUT + jj];
        #pragma unroll
        for (int i = 0; i < 8; ++i) acc[i] += xr[i * DOUT + k] * w;
    }

    if (j < DOUT) {
        #pragma unroll
        for (int i = 0; i < 8; ++i) h[(size_t)(nb + i) * DOUT + jj] = acc[i];
    } else {
        #pragma unroll
        for (int i = 0; i < 8; ++i) out[(size_t)(nb + i) * DOUT + jj] = acc[i];
    }
}

// ---- K1b: per-node attention dots: as[n,h]=<h[n,h,:],a_src[h]>, ad likewise ----
__global__ __launch_bounds__(256) void k_attdot(const float* __restrict__ h,
                                                const float* __restrict__ att,
                                                float* __restrict__ as_,
                                                float* __restrict__ ad_) {
    int nh = blockIdx.x * 256 + threadIdx.x;
    if (nh >= N_NODES * NHEAD) return;
    int n = nh >> 2, hd = nh & 3;
    const float4* hv = (const float4*)(h + (size_t)n * DOUT + hd * DHEAD);
    const float4* a1 = (const float4*)(att + hd * 2 * DHEAD);          // a_src
    const float4* a2 = (const float4*)(att + hd * 2 * DHEAD + DHEAD);  // a_dst
    float s1 = 0.0f, s2 = 0.0f;
    #pragma unroll
    for (int q = 0; q < DHEAD / 4; ++q) {
        float4 v = hv[q], x1 = a1[q], x2 = a2[q];
        s1 += v.x * x1.x + v.y * x1.y + v.z * x1.z + v.w * x1.w;
        s2 += v.x * x2.x + v.y * x2.y + v.z * x2.z + v.w * x2.w;
    }
    as_[nh] = s1;
    ad_[nh] = s2;
}

// ---- K2: per-edge segment_max via atomicMax on encoded floats ----
__global__ __launch_bounds__(256) void k_max(const int* __restrict__ ei,
                                             const int* __restrict__ flag,
                                             const float* __restrict__ as_,
                                             const float* __restrict__ ad_,
                                             unsigned* __restrict__ emax) {
    int e = blockIdx.x * 256 + threadIdx.x;
    if (e >= E_EDGES) return;
    int isI64 = *flag;
    int src, dst;
    load_edge(ei, isI64, e, src, dst);
    if ((unsigned)src >= N_NODES || (unsigned)dst >= N_NODES) return;  // safety
    float4 a1 = *(const float4*)(as_ + (size_t)src * 4);
    float4 a2 = *(const float4*)(ad_ + (size_t)dst * 4);
    float e0 = a1.x + a2.x; e0 = (e0 > 0.0f) ? e0 : NEG_SLOPE * e0;
    float e1 = a1.y + a2.y; e1 = (e1 > 0.0f) ? e1 : NEG_SLOPE * e1;
    float e2 = a1.z + a2.z; e2 = (e2 > 0.0f) ? e2 : NEG_SLOPE * e2;
    float e3 = a1.w + a2.w; e3 = (e3 > 0.0f) ? e3 : NEG_SLOPE * e3;
    unsigned* base = emax + (size_t)dst * 4;
    atomicMax(base + 0, fenc(e0));
    atomicMax(base + 1, fenc(e1));
    atomicMax(base + 2, fenc(e2));
    atomicMax(base + 3, fenc(e3));
}

// ---- K3: per-edge exp + scatter-accumulate numerator & denominator ----
// 2 edges per 256-thread block; 128 threads per edge cover (h,d).
__global__ __launch_bounds__(256) void k_acc(const int* __restrict__ ei,
                                             const int* __restrict__ flag,
                                             const float* __restrict__ as_,
                                             const float* __restrict__ ad_,
                                             const unsigned* __restrict__ emax,
                                             const float* __restrict__ h,
                                             float* __restrict__ num,
                                             float* __restrict__ den) {
    int e = blockIdx.x * 2 + (threadIdx.x >> 7);
    int k = threadIdx.x & 127;
    int hd = k >> 5, d = k & 31;
    int isI64 = *flag;
    int src, dst;
    load_edge(ei, isI64, e, src, dst);
    if ((unsigned)src >= N_NODES || (unsigned)dst >= N_NODES) return;  // safety
    float el = as_[(size_t)src * 4 + hd] + ad_[(size_t)dst * 4 + hd];
    el = (el > 0.0f) ? el : NEG_SLOPE * el;
    float m = fdec(emax[(size_t)dst * 4 + hd]);
    float p = __expf(el - m);
    float hv = h[(size_t)src * DOUT + k];
    atomicAdd(num + (size_t)dst * DOUT + k, p * hv);
    if (d == 0) atomicAdd(den + (size_t)dst * 4 + hd, p);
}

// ---- K4: finalize: out = num/(den+eps) + skip(out) ----
__global__ __launch_bounds__(256) void k_fin(const float* __restrict__ num,
                                             const float* __restrict__ den,
                                             float* __restrict__ out) {
    int idx = blockIdx.x * 256 + threadIdx.x;
    if (idx >= N_NODES * DOUT) return;
    int n = idx >> 7, hd = (idx >> 5) & 3;
    out[idx] = num[idx] / (den[(size_t)n * 4 + hd] + EPS_F) + out[idx];
}

extern "C" void kernel_launch(void* const* d_in, const int* in_sizes, int n_in,
                              void* d_out, int out_size, void* d_ws, size_t ws_size,
                              hipStream_t stream) {
    const float* x   = (const float*)d_in[0];
    const float* Wp  = (const float*)d_in[1];
    const float* att = (const float*)d_in[2];
    const float* Ws  = (const float*)d_in[3];
    const int*   ei  = (const int*)d_in[4];
    float* out = (float*)d_out;

    char* ws = (char*)d_ws;
    const size_t HBYTES = (size_t)N_NODES * DOUT * 4;   // 25,600,000
    float*    h    = (float*)(ws);
    float*    num  = (float*)(ws + HBYTES);
    float*    as_  = (float*)(ws + 2 * HBYTES);
    float*    ad_  = (float*)(ws + 2 * HBYTES + 800000);
    unsigned* emax = (unsigned*)(ws + 2 * HBYTES + 1600000);
    float*    den  = (float*)(ws + 2 * HBYTES + 2400000);
    int*      flag = (int*)(ws + 2 * HBYTES + 3200000);

    hipMemsetAsync(num, 0, HBYTES, stream);
    hipMemsetAsync(emax, 0, (size_t)N_NODES * 4 * 4, stream);
    hipMemsetAsync(den, 0, (size_t)N_NODES * 4 * 4, stream);

    k_detect<<<1, 256, 0, stream>>>(ei, flag);
    k_gemm<<<N_NODES / 8, 256, 0, stream>>>(x, Wp, Ws, h, out);
    k_attdot<<<(N_NODES * NHEAD + 255) / 256, 256, 0, stream>>>(h, att, as_, ad_);
    k_max<<<E_EDGES / 256, 256, 0, stream>>>(ei, flag, as_, ad_, emax);
    k_acc<<<E_EDGES / 2, 256, 0, stream>>>(ei, flag, as_, ad_, emax, h, num, den);
    k_fin<<<(N_NODES * DOUT) / 256, 256, 0, stream>>>(num, den, out);
}

// Round 2
// 429.308 us; speedup vs baseline: 1.5523x; 1.5523x over previous
//
#include <hip/hip_runtime.h>
#include <hip/hip_bf16.h>

#define N_NODES 50000
#define E_EDGES 800000
#define NHEAD 4
#define DHEAD 32
#define DOUT 128   // NHEAD*DHEAD == D_IN
#define NEG_SLOPE 0.01f
#define EPS_F 1e-16f

// ---- edge index fetch, robust to int32 vs int64 storage ----
// If edge_index is int64 (little-endian, values < 2^31), the int32 view is
// [lo0, 0, lo1, 0, ...]. Flag==1 means int64 layout.
__device__ __forceinline__ void load_edge(const int* __restrict__ ei, int isI64,
                                          int e, int& src, int& dst) {
    if (isI64) { src = ei[2 * e]; dst = ei[2 * (E_EDGES + e)]; }
    else       { src = ei[e];     dst = ei[E_EDGES + e]; }
}

// Detect int64-vs-int32: sample 2048 odd int32 positions; all zero => int64.
__global__ void k_detect(const int* __restrict__ ei, int* __restrict__ flag) {
    __shared__ int cnt;
    if (threadIdx.x == 0) cnt = 0;
    __syncthreads();
    int nz = 0;
    #pragma unroll
    for (int k = 0; k < 8; ++k) {
        int pos = (threadIdx.x + k * 256) * 2 + 1;   // < 4096, in-bounds either way
        if (ei[pos] != 0) nz = 1;
    }
    if (nz) atomicOr(&cnt, 1);
    __syncthreads();
    if (threadIdx.x == 0) *flag = (cnt == 0) ? 1 : 0;
}

// ---- K1: fused GEMM: h = x@W_proj, out(skip) = x@W_skip ----
__global__ __launch_bounds__(256) void k_gemm(const float* __restrict__ x,
                                              const float* __restrict__ Wp,
                                              const float* __restrict__ Ws,
                                              float* __restrict__ h,
                                              float* __restrict__ out) {
    const int j = threadIdx.x;             // 0..255 over [W_proj | W_skip] cols
    const int nb = blockIdx.x * 8;         // 6250*8 == 50000 exactly
    const float* __restrict__ W = (j < DOUT) ? Wp : Ws;
    const int jj = j & (DOUT - 1);
    const float* __restrict__ xr = x + (size_t)nb * DOUT;

    float acc[8];
    #pragma unroll
    for (int i = 0; i < 8; ++i) acc[i] = 0.0f;

    #pragma unroll 4
    for (int k = 0; k < DOUT; ++k) {
        float w = W[k * DOUT + jj];
        #pragma unroll
        for (int i = 0; i < 8; ++i) acc[i] += xr[i * DOUT + k] * w;
    }

    if (j < DOUT) {
        #pragma unroll
        for (int i = 0; i < 8; ++i) h[(size_t)(nb + i) * DOUT + jj] = acc[i];
    } else {
        #pragma unroll
        for (int i = 0; i < 8; ++i) out[(size_t)(nb + i) * DOUT + jj] = acc[i];
    }
}

// ---- K1b: per-node attention dots ----
__global__ __launch_bounds__(256) void k_attdot(const float* __restrict__ h,
                                                const float* __restrict__ att,
                                                float* __restrict__ as_,
                                                float* __restrict__ ad_) {
    int nh = blockIdx.x * 256 + threadIdx.x;
    if (nh >= N_NODES * NHEAD) return;
    int n = nh >> 2, hd = nh & 3;
    const float4* hv = (const float4*)(h + (size_t)n * DOUT + hd * DHEAD);
    const float4* a1 = (const float4*)(att + hd * 2 * DHEAD);          // a_src
    const float4* a2 = (const float4*)(att + hd * 2 * DHEAD + DHEAD);  // a_dst
    float s1 = 0.0f, s2 = 0.0f;
    #pragma unroll
    for (int q = 0; q < DHEAD / 4; ++q) {
        float4 v = hv[q], x1 = a1[q], x2 = a2[q];
        s1 += v.x * x1.x + v.y * x1.y + v.z * x1.z + v.w * x1.w;
        s2 += v.x * x2.x + v.y * x2.y + v.z * x2.z + v.w * x2.w;
    }
    as_[nh] = s1;
    ad_[nh] = s2;
}

// ---- K2a: histogram of dst ----
__global__ __launch_bounds__(256) void k_hist(const int* __restrict__ ei,
                                              const int* __restrict__ flag,
                                              int* __restrict__ deg) {
    int e = blockIdx.x * 256 + threadIdx.x;
    if (e >= E_EDGES) return;
    int src, dst;
    load_edge(ei, *flag, e, src, dst);
    if ((unsigned)dst >= N_NODES) return;
    atomicAdd(deg + dst, 1);
}

// ---- K2b: single-block exclusive scan of deg -> ofs, cursor ----
#define SCAN_T 1024
#define SCAN_C 49   // 1024*49 >= 50000
__global__ __launch_bounds__(SCAN_T) void k_scan(const int* __restrict__ deg,
                                                 int* __restrict__ ofs,
                                                 int* __restrict__ cursor) {
    __shared__ int part[SCAN_T];
    int t = threadIdx.x;
    int lo = t * SCAN_C;
    int hi = lo + SCAN_C; if (hi > N_NODES) hi = N_NODES;
    int s = 0;
    for (int i = lo; i < hi; ++i) s += deg[i];
    part[t] = s;
    __syncthreads();
    for (int off = 1; off < SCAN_T; off <<= 1) {
        int v = (t >= off) ? part[t - off] : 0;
        __syncthreads();
        part[t] += v;
        __syncthreads();
    }
    int run = part[t] - s;   // exclusive
    for (int i = lo; i < hi; ++i) {
        ofs[i] = run; cursor[i] = run; run += deg[i];
    }
}

// ---- K2c: scatter edges into CSR order ----
__global__ __launch_bounds__(256) void k_scatter(const int* __restrict__ ei,
                                                 const int* __restrict__ flag,
                                                 int* __restrict__ cursor,
                                                 int* __restrict__ srcs) {
    int e = blockIdx.x * 256 + threadIdx.x;
    if (e >= E_EDGES) return;
    int src, dst;
    load_edge(ei, *flag, e, src, dst);
    if ((unsigned)src >= N_NODES || (unsigned)dst >= N_NODES) return;
    int pos = atomicAdd(cursor + dst, 1);
    srcs[pos] = src;
}

// ---- K3: gather-accumulate per dst node (fuses max, exp, denom, div, skip) ----
// One 128-thread block per node; thread k owns output element k (head hd=k>>5).
__global__ __launch_bounds__(128) void k_gat(const int* __restrict__ ofs,
                                             const int* __restrict__ deg,
                                             const int* __restrict__ srcs,
                                             const float* __restrict__ as_,
                                             const float* __restrict__ ad_,
                                             const float* __restrict__ h,
                                             float* __restrict__ out) {
    const int n = blockIdx.x;
    const int k = threadIdx.x;          // 0..127
    const int hd = k >> 5;
    const int o = ofs[n];
    const int d = deg[n];
    const float adv = ad_[(size_t)n * 4 + hd];

    // pass 1: per-head max (each lane of a head group computes redundantly)
    float m = -3.4e38f;
    for (int i = 0; i < d; ++i) {
        int s = srcs[o + i];
        float el = as_[(size_t)s * 4 + hd] + adv;
        el = (el > 0.0f) ? el : NEG_SLOPE * el;
        m = fmaxf(m, el);
    }

    // pass 2: accumulate numerator (own element) + denominator (redundant)
    float num = 0.0f, den = 0.0f;
    for (int i = 0; i < d; ++i) {
        int s = srcs[o + i];
        float el = as_[(size_t)s * 4 + hd] + adv;
        el = (el > 0.0f) ? el : NEG_SLOPE * el;
        float p = __expf(el - m);
        den += p;
        num += p * h[(size_t)s * DOUT + k];
    }

    size_t oi = (size_t)n * DOUT + k;
    out[oi] = num / (den + EPS_F) + out[oi];   // out already holds skip
}

extern "C" void kernel_launch(void* const* d_in, const int* in_sizes, int n_in,
                              void* d_out, int out_size, void* d_ws, size_t ws_size,
                              hipStream_t stream) {
    const float* x   = (const float*)d_in[0];
    const float* Wp  = (const float*)d_in[1];
    const float* att = (const float*)d_in[2];
    const float* Ws  = (const float*)d_in[3];
    const int*   ei  = (const int*)d_in[4];
    float* out = (float*)d_out;

    char* ws = (char*)d_ws;
    const size_t HBYTES = (size_t)N_NODES * DOUT * 4;   // 25,600,000
    float* h      = (float*)(ws);
    float* as_    = (float*)(ws + HBYTES);
    float* ad_    = (float*)(ws + HBYTES + 800000);
    int*   deg    = (int*)(ws + HBYTES + 1600000);
    int*   ofs    = (int*)(ws + HBYTES + 1800000);
    int*   cursor = (int*)(ws + HBYTES + 2000000);
    int*   srcs   = (int*)(ws + HBYTES + 2200000);
    int*   flag   = (int*)(ws + HBYTES + 2200000 + 3200000);

    hipMemsetAsync(deg, 0, (size_t)N_NODES * 4, stream);

    k_detect<<<1, 256, 0, stream>>>(ei, flag);
    k_gemm<<<N_NODES / 8, 256, 0, stream>>>(x, Wp, Ws, h, out);
    k_attdot<<<(N_NODES * NHEAD + 255) / 256, 256, 0, stream>>>(h, att, as_, ad_);
    k_hist<<<(E_EDGES + 255) / 256, 256, 0, stream>>>(ei, flag, deg);
    k_scan<<<1, SCAN_T, 0, stream>>>(deg, ofs, cursor);
    k_scatter<<<(E_EDGES + 255) / 256, 256, 0, stream>>>(ei, flag, cursor, srcs);
    k_gat<<<N_NODES, 128, 0, stream>>>(ofs, deg, srcs, as_, ad_, h, out);
}

// Round 3
// 381.489 us; speedup vs baseline: 1.7468x; 1.1253x over previous
//
#include <hip/hip_runtime.h>
#include <hip/hip_bf16.h>

#define N_NODES 50000
#define E_EDGES 800000
#define NHEAD 4
#define DHEAD 32
#define DOUT 128   // NHEAD*DHEAD == D_IN
#define NEG_SLOPE 0.01f
#define EPS_F 1e-16f
#define DMAX 512   // per-node degree handled via LDS fast path

__device__ __forceinline__ float bf2f(unsigned short u) {
    return __uint_as_float((unsigned)u << 16);
}

// ---- edge index fetch, robust to int32 vs int64 storage ----
__device__ __forceinline__ void load_edge(const int* __restrict__ ei, int isI64,
                                          int e, int& src, int& dst) {
    if (isI64) { src = ei[2 * e]; dst = ei[2 * (E_EDGES + e)]; }
    else       { src = ei[e];     dst = ei[E_EDGES + e]; }
}

// Detect int64-vs-int32: sample 2048 odd int32 positions; all zero => int64.
__global__ void k_detect(const int* __restrict__ ei, int* __restrict__ flag) {
    __shared__ int cnt;
    if (threadIdx.x == 0) cnt = 0;
    __syncthreads();
    int nz = 0;
    #pragma unroll
    for (int k = 0; k < 8; ++k) {
        int pos = (threadIdx.x + k * 256) * 2 + 1;
        if (ei[pos] != 0) nz = 1;
    }
    if (nz) atomicOr(&cnt, 1);
    __syncthreads();
    if (threadIdx.x == 0) *flag = (cnt == 0) ? 1 : 0;
}

// ---- K1: fused GEMM: h = x@W_proj (f32 + bf16 copies), out(skip) = x@W_skip ----
// 16 nodes per block (3125 blocks exactly), 256 threads = one col of [Wp|Ws].
__global__ __launch_bounds__(256) void k_gemm(const float* __restrict__ x,
                                              const float* __restrict__ Wp,
                                              const float* __restrict__ Ws,
                                              float* __restrict__ h,
                                              unsigned short* __restrict__ hb,
                                              float* __restrict__ out) {
    const int j = threadIdx.x;
    const int nb = blockIdx.x * 16;        // 3125*16 == 50000 exactly
    const float* __restrict__ W = (j < DOUT) ? Wp : Ws;
    const int jj = j & (DOUT - 1);
    const float* __restrict__ xr = x + (size_t)nb * DOUT;

    float acc[16];
    #pragma unroll
    for (int i = 0; i < 16; ++i) acc[i] = 0.0f;

    #pragma unroll 2
    for (int k = 0; k < DOUT; ++k) {
        float w = W[k * DOUT + jj];
        #pragma unroll
        for (int i = 0; i < 16; ++i) acc[i] += xr[i * DOUT + k] * w;
    }

    if (j < DOUT) {
        #pragma unroll
        for (int i = 0; i < 16; ++i) {
            size_t o = (size_t)(nb + i) * DOUT + jj;
            h[o] = acc[i];
            hb[o] = __bfloat16_as_ushort(__float2bfloat16(acc[i]));
        }
    } else {
        #pragma unroll
        for (int i = 0; i < 16; ++i) out[(size_t)(nb + i) * DOUT + jj] = acc[i];
    }
}

// ---- K1b: per-node attention dots (reads exact f32 h) ----
__global__ __launch_bounds__(256) void k_attdot(const float* __restrict__ h,
                                                const float* __restrict__ att,
                                                float* __restrict__ as_,
                                                float* __restrict__ ad_) {
    int nh = blockIdx.x * 256 + threadIdx.x;
    if (nh >= N_NODES * NHEAD) return;
    int n = nh >> 2, hd = nh & 3;
    const float4* hv = (const float4*)(h + (size_t)n * DOUT + hd * DHEAD);
    const float4* a1 = (const float4*)(att + hd * 2 * DHEAD);
    const float4* a2 = (const float4*)(att + hd * 2 * DHEAD + DHEAD);
    float s1 = 0.0f, s2 = 0.0f;
    #pragma unroll
    for (int q = 0; q < DHEAD / 4; ++q) {
        float4 v = hv[q], x1 = a1[q], x2 = a2[q];
        s1 += v.x * x1.x + v.y * x1.y + v.z * x1.z + v.w * x1.w;
        s2 += v.x * x2.x + v.y * x2.y + v.z * x2.z + v.w * x2.w;
    }
    as_[nh] = s1;
    ad_[nh] = s2;
}

// ---- K2a: histogram of dst ----
__global__ __launch_bounds__(256) void k_hist(const int* __restrict__ ei,
                                              const int* __restrict__ flag,
                                              int* __restrict__ deg) {
    int e = blockIdx.x * 256 + threadIdx.x;
    if (e >= E_EDGES) return;
    int src, dst;
    load_edge(ei, *flag, e, src, dst);
    if ((unsigned)dst >= N_NODES) return;
    atomicAdd(deg + dst, 1);
}

// ---- K2b: single-block exclusive scan ----
#define SCAN_T 1024
#define SCAN_C 49
__global__ __launch_bounds__(SCAN_T) void k_scan(const int* __restrict__ deg,
                                                 int* __restrict__ ofs,
                                                 int* __restrict__ cursor) {
    __shared__ int part[SCAN_T];
    int t = threadIdx.x;
    int lo = t * SCAN_C;
    int hi = lo + SCAN_C; if (hi > N_NODES) hi = N_NODES;
    int s = 0;
    for (int i = lo; i < hi; ++i) s += deg[i];
    part[t] = s;
    __syncthreads();
    for (int off = 1; off < SCAN_T; off <<= 1) {
        int v = (t >= off) ? part[t - off] : 0;
        __syncthreads();
        part[t] += v;
        __syncthreads();
    }
    int run = part[t] - s;
    for (int i = lo; i < hi; ++i) {
        ofs[i] = run; cursor[i] = run; run += deg[i];
    }
}

// ---- K2c: scatter edges into CSR order ----
__global__ __launch_bounds__(256) void k_scatter(const int* __restrict__ ei,
                                                 const int* __restrict__ flag,
                                                 int* __restrict__ cursor,
                                                 int* __restrict__ srcs) {
    int e = blockIdx.x * 256 + threadIdx.x;
    if (e >= E_EDGES) return;
    int src, dst;
    load_edge(ei, *flag, e, src, dst);
    if ((unsigned)src >= N_NODES || (unsigned)dst >= N_NODES) return;
    int pos = atomicAdd(cursor + dst, 1);
    srcs[pos] = src;
}

// ---- K3: per-node gather. el/exp computed ONCE per (edge,head) in LDS. ----
// 128 threads per node: thread k owns output col k; head hd=k>>5, lane l=k&31.
__global__ __launch_bounds__(128) void k_gat(const int* __restrict__ ofs,
                                             const int* __restrict__ deg,
                                             const int* __restrict__ srcs,
                                             const float* __restrict__ as_,
                                             const float* __restrict__ ad_,
                                             const float* __restrict__ h,
                                             const unsigned short* __restrict__ hb,
                                             float* __restrict__ out) {
    __shared__ float EL[DMAX * NHEAD];   // 8 KB: el -> p, indexed [i*4+hd]
    __shared__ int   SRC[DMAX];          // 2 KB

    const int n = blockIdx.x;
    const int k = threadIdx.x;
    const int hd = k >> 5;
    const int l = k & 31;
    const int o = ofs[n];
    const int d = deg[n];
    size_t oi = (size_t)n * DOUT + k;

    if (d <= DMAX) {
        // phase A: stage srcs
        for (int i = k; i < d; i += 128) SRC[i] = srcs[o + i];
        __syncthreads();
        // phase B: el for each (edge, head) work item
        const float4 adv4 = *(const float4*)(ad_ + (size_t)n * 4);
        const float adv_arr[4] = {adv4.x, adv4.y, adv4.z, adv4.w};
        for (int w = k; w < d * NHEAD; w += 128) {
            int e = w >> 2, hh = w & 3;
            float el = as_[(size_t)SRC[e] * 4 + hh] + adv_arr[hh];
            EL[w] = (el > 0.0f) ? el : NEG_SLOPE * el;
        }
        __syncthreads();
        // phase C: per-head max, then p=exp(el-m) in place, then denom
        float m = -3.4e38f;
        for (int i = l; i < d; i += 32) m = fmaxf(m, EL[i * 4 + hd]);
        #pragma unroll
        for (int off = 16; off; off >>= 1) m = fmaxf(m, __shfl_xor(m, off));
        float den = 0.0f;
        for (int i = l; i < d; i += 32) {
            float p = __expf(EL[i * 4 + hd] - m);
            EL[i * 4 + hd] = p;
            den += p;
        }
        #pragma unroll
        for (int off = 16; off; off >>= 1) den += __shfl_xor(den, off);
        __syncthreads();
        // phase D: weighted gather of bf16 h rows
        float num = 0.0f;
        for (int i = 0; i < d; ++i) {
            float p = EL[i * 4 + hd];
            int s = SRC[i];
            num = fmaf(p, bf2f(hb[(size_t)s * DOUT + k]), num);
        }
        out[oi] = num / (den + EPS_F) + out[oi];
    } else {
        // fallback (degree > DMAX): redundant two-pass, exact f32
        const float adv = ad_[(size_t)n * 4 + hd];
        float m = -3.4e38f;
        for (int i = 0; i < d; ++i) {
            float el = as_[(size_t)srcs[o + i] * 4 + hd] + adv;
            el = (el > 0.0f) ? el : NEG_SLOPE * el;
            m = fmaxf(m, el);
        }
        float num = 0.0f, den = 0.0f;
        for (int i = 0; i < d; ++i) {
            int s = srcs[o + i];
            float el = as_[(size_t)s * 4 + hd] + adv;
            el = (el > 0.0f) ? el : NEG_SLOPE * el;
            float p = __expf(el - m);
            den += p;
            num += p * h[(size_t)s * DOUT + k];
        }
        out[oi] = num / (den + EPS_F) + out[oi];
    }
}

extern "C" void kernel_launch(void* const* d_in, const int* in_sizes, int n_in,
                              void* d_out, int out_size, void* d_ws, size_t ws_size,
                              hipStream_t stream) {
    const float* x   = (const float*)d_in[0];
    const float* Wp  = (const float*)d_in[1];
    const float* att = (const float*)d_in[2];
    const float* Ws  = (const float*)d_in[3];
    const int*   ei  = (const int*)d_in[4];
    float* out = (float*)d_out;

    char* ws = (char*)d_ws;
    float*          h      = (float*)(ws);                       // 25.6 MB
    unsigned short* hb     = (unsigned short*)(ws + 25600000);   // 12.8 MB
    float*          as_    = (float*)(ws + 38400000);            // 0.8 MB
    float*          ad_    = (float*)(ws + 39200000);            // 0.8 MB
    int*            deg    = (int*)(ws + 40000000);              // 0.2 MB
    int*            ofs    = (int*)(ws + 40200000);              // 0.2 MB
    int*            cursor = (int*)(ws + 40400000);              // 0.2 MB
    int*            srcs   = (int*)(ws + 40600000);              // 3.2 MB
    int*            flag   = (int*)(ws + 43800000);

    hipMemsetAsync(deg, 0, (size_t)N_NODES * 4, stream);

    k_detect<<<1, 256, 0, stream>>>(ei, flag);
    k_gemm<<<N_NODES / 16, 256, 0, stream>>>(x, Wp, Ws, h, hb, out);
    k_attdot<<<(N_NODES * NHEAD + 255) / 256, 256, 0, stream>>>(h, att, as_, ad_);
    k_hist<<<(E_EDGES + 255) / 256, 256, 0, stream>>>(ei, flag, deg);
    k_scan<<<1, SCAN_T, 0, stream>>>(deg, ofs, cursor);
    k_scatter<<<(E_EDGES + 255) / 256, 256, 0, stream>>>(ei, flag, cursor, srcs);
    k_gat<<<N_NODES, 128, 0, stream>>>(ofs, deg, srcs, as_, ad_, h, hb, out);
}

// Round 4
// 320.879 us; speedup vs baseline: 2.0768x; 1.1889x over previous
//
#include <hip/hip_runtime.h>
#include <hip/hip_bf16.h>

#define N_NODES 50000
#define E_EDGES 800000
#define NHEAD 4
#define DHEAD 32
#define DOUT 128   // NHEAD*DHEAD == D_IN
#define NEG_SLOPE 0.01f
#define EPS_F 1e-16f
#define DMAX 512

typedef __attribute__((ext_vector_type(8))) short bf16x8;
typedef __attribute__((ext_vector_type(4))) float f32x4;

__device__ __forceinline__ float bf2f(unsigned short u) {
    return __uint_as_float((unsigned)u << 16);
}
__device__ __forceinline__ unsigned short f2bf(float f) {
    return __bfloat16_as_ushort(__float2bfloat16(f));   // RNE
}

// ---- edge index fetch, robust to int32 vs int64 storage ----
__device__ __forceinline__ void load_edge(const int* __restrict__ ei, int isI64,
                                          int e, int& src, int& dst) {
    if (isI64) { src = ei[2 * e]; dst = ei[2 * (E_EDGES + e)]; }
    else       { src = ei[e];     dst = ei[E_EDGES + e]; }
}

// Detect int64-vs-int32: sample 2048 odd int32 positions; all zero => int64.
__global__ void k_detect(const int* __restrict__ ei, int* __restrict__ flag) {
    __shared__ int cnt;
    if (threadIdx.x == 0) cnt = 0;
    __syncthreads();
    int nz = 0;
    #pragma unroll
    for (int k = 0; k < 8; ++k) {
        int pos = (threadIdx.x + k * 256) * 2 + 1;
        if (ei[pos] != 0) nz = 1;
    }
    if (nz) atomicOr(&cnt, 1);
    __syncthreads();
    if (threadIdx.x == 0) *flag = (cnt == 0) ? 1 : 0;
}

// ---- K0: transpose+cvt weights: Wt[c][k] bf16, c in [0,256) over [Wp|Ws] ----
__global__ void k_prepw(const float* __restrict__ Wp, const float* __restrict__ Ws,
                        unsigned short* __restrict__ Wt) {
    int c = blockIdx.x;     // 0..255
    int k = threadIdx.x;    // 0..127
    float v = (c < DOUT) ? Wp[k * DOUT + c] : Ws[k * DOUT + (c - DOUT)];
    Wt[c * DOUT + k] = f2bf(v);
}

// ---- K1: MFMA GEMM: [hb | out] = bf16(x) @ [Wp | Ws]  (no LDS, no barriers)
// 4 waves/block, 16 rows/wave. A from f32 x (cvt in-flight), B from Wt (L2).
// A-frag: row=lane&15, k=(lane>>4)*8+e.  B-frag: col=lane&15, same k.
// C/D: col=lane&15, row=(lane>>4)*4+reg  [measured: learn_hip m89].
__global__ __launch_bounds__(256) void k_gemm(const float* __restrict__ x,
                                              const unsigned short* __restrict__ Wt,
                                              unsigned short* __restrict__ hb,
                                              float* __restrict__ out) {
    const int wid = threadIdx.x >> 6;
    const int l   = threadIdx.x & 63;
    const int l15 = l & 15;
    const int lq  = l >> 4;             // 0..3
    const int rowbase = blockIdx.x * 64 + wid * 16;
    const int koff = lq * 8;

    // A fragments for all 4 K-steps
    int arow = rowbase + l15;
    if (arow > N_NODES - 1) arow = N_NODES - 1;
    const float* __restrict__ xr = x + (size_t)arow * DOUT;
    bf16x8 afr[4];
    #pragma unroll
    for (int ks = 0; ks < 4; ++ks) {
        float4 u0 = *(const float4*)(xr + ks * 32 + koff);
        float4 u1 = *(const float4*)(xr + ks * 32 + koff + 4);
        bf16x8 a;
        a[0] = (short)f2bf(u0.x); a[1] = (short)f2bf(u0.y);
        a[2] = (short)f2bf(u0.z); a[3] = (short)f2bf(u0.w);
        a[4] = (short)f2bf(u1.x); a[5] = (short)f2bf(u1.y);
        a[6] = (short)f2bf(u1.z); a[7] = (short)f2bf(u1.w);
        afr[ks] = a;
    }

    f32x4 acc[16];
    #pragma unroll
    for (int nf = 0; nf < 16; ++nf) acc[nf] = (f32x4)(0.0f);

    #pragma unroll
    for (int nf = 0; nf < 16; ++nf) {
        const unsigned short* wp = Wt + (size_t)(nf * 16 + l15) * DOUT + koff;
        #pragma unroll
        for (int ks = 0; ks < 4; ++ks) {
            bf16x8 b = *(const bf16x8*)(wp + ks * 32);
            acc[nf] = __builtin_amdgcn_mfma_f32_16x16x32_bf16(afr[ks], b, acc[nf], 0, 0, 0);
        }
    }

    #pragma unroll
    for (int nf = 0; nf < 16; ++nf) {
        #pragma unroll
        for (int q = 0; q < 4; ++q) {
            int row = rowbase + lq * 4 + q;
            if (row < N_NODES) {
                if (nf < 8)
                    hb[(size_t)row * DOUT + nf * 16 + l15] = f2bf(acc[nf][q]);
                else
                    out[(size_t)row * DOUT + (nf - 8) * 16 + l15] = acc[nf][q];
            }
        }
    }
}

// ---- K1b: per-node attention dots (reads bf16 hb) ----
__global__ __launch_bounds__(256) void k_attdot(const unsigned short* __restrict__ hb,
                                                const float* __restrict__ att,
                                                float* __restrict__ as_,
                                                float* __restrict__ ad_) {
    int nh = blockIdx.x * 256 + threadIdx.x;
    if (nh >= N_NODES * NHEAD) return;
    int n = nh >> 2, hd = nh & 3;
    const uint4* hv = (const uint4*)(hb + (size_t)n * DOUT + hd * DHEAD);
    const float* a1 = att + hd * 2 * DHEAD;
    const float* a2 = a1 + DHEAD;
    float s1 = 0.0f, s2 = 0.0f;
    #pragma unroll
    for (int q = 0; q < 4; ++q) {
        uint4 u = hv[q];
        unsigned vv[4] = {u.x, u.y, u.z, u.w};
        #pragma unroll
        for (int t = 0; t < 4; ++t) {
            float lo = bf2f((unsigned short)(vv[t] & 0xffff));
            float hi = bf2f((unsigned short)(vv[t] >> 16));
            int j = q * 8 + t * 2;
            s1 += lo * a1[j] + hi * a1[j + 1];
            s2 += lo * a2[j] + hi * a2[j + 1];
        }
    }
    as_[nh] = s1;
    ad_[nh] = s2;
}

// ---- K2a: histogram of dst ----
__global__ __launch_bounds__(256) void k_hist(const int* __restrict__ ei,
                                              const int* __restrict__ flag,
                                              int* __restrict__ deg) {
    int e = blockIdx.x * 256 + threadIdx.x;
    if (e >= E_EDGES) return;
    int src, dst;
    load_edge(ei, *flag, e, src, dst);
    if ((unsigned)dst >= N_NODES) return;
    atomicAdd(deg + dst, 1);
}

// ---- K2b: single-block exclusive scan ----
#define SCAN_T 1024
#define SCAN_C 49
__global__ __launch_bounds__(SCAN_T) void k_scan(const int* __restrict__ deg,
                                                 int* __restrict__ ofs,
                                                 int* __restrict__ cursor) {
    __shared__ int part[SCAN_T];
    int t = threadIdx.x;
    int lo = t * SCAN_C;
    int hi = lo + SCAN_C; if (hi > N_NODES) hi = N_NODES;
    int s = 0;
    for (int i = lo; i < hi; ++i) s += deg[i];
    part[t] = s;
    __syncthreads();
    for (int off = 1; off < SCAN_T; off <<= 1) {
        int v = (t >= off) ? part[t - off] : 0;
        __syncthreads();
        part[t] += v;
        __syncthreads();
    }
    int run = part[t] - s;
    for (int i = lo; i < hi; ++i) {
        ofs[i] = run; cursor[i] = run; run += deg[i];
    }
}

// ---- K2c: scatter edges into CSR order ----
__global__ __launch_bounds__(256) void k_scatter(const int* __restrict__ ei,
                                                 const int* __restrict__ flag,
                                                 int* __restrict__ cursor,
                                                 int* __restrict__ srcs) {
    int e = blockIdx.x * 256 + threadIdx.x;
    if (e >= E_EDGES) return;
    int src, dst;
    load_edge(ei, *flag, e, src, dst);
    if ((unsigned)src >= N_NODES || (unsigned)dst >= N_NODES) return;
    int pos = atomicAdd(cursor + dst, 1);
    srcs[pos] = src;
}

// ---- K3: per-node gather: el/exp once per (edge,head) in LDS, bf16 h rows ----
__global__ __launch_bounds__(128) void k_gat(const int* __restrict__ ofs,
                                             const int* __restrict__ deg,
                                             const int* __restrict__ srcs,
                                             const float* __restrict__ as_,
                                             const float* __restrict__ ad_,
                                             const unsigned short* __restrict__ hb,
                                             float* __restrict__ out) {
    __shared__ float EL[DMAX * NHEAD];   // 8 KB
    __shared__ int   SRC[DMAX];          // 2 KB

    const int n = blockIdx.x;
    const int k = threadIdx.x;
    const int hd = k >> 5;
    const int l = k & 31;
    const int o = ofs[n];
    const int d = deg[n];
    size_t oi = (size_t)n * DOUT + k;

    if (d <= DMAX) {
        for (int i = k; i < d; i += 128) SRC[i] = srcs[o + i];
        __syncthreads();
        const float4 adv4 = *(const float4*)(ad_ + (size_t)n * 4);
        const float adv_arr[4] = {adv4.x, adv4.y, adv4.z, adv4.w};
        for (int w = k; w < d * NHEAD; w += 128) {
            int e = w >> 2, hh = w & 3;
            float el = as_[(size_t)SRC[e] * 4 + hh] + adv_arr[hh];
            EL[w] = (el > 0.0f) ? el : NEG_SLOPE * el;
        }
        __syncthreads();
        float m = -3.4e38f;
        for (int i = l; i < d; i += 32) m = fmaxf(m, EL[i * 4 + hd]);
        #pragma unroll
        for (int off = 16; off; off >>= 1) m = fmaxf(m, __shfl_xor(m, off));
        float den = 0.0f;
        for (int i = l; i < d; i += 32) {
            float p = __expf(EL[i * 4 + hd] - m);
            EL[i * 4 + hd] = p;
            den += p;
        }
        #pragma unroll
        for (int off = 16; off; off >>= 1) den += __shfl_xor(den, off);
        __syncthreads();
        float num = 0.0f;
        for (int i = 0; i < d; ++i) {
            float p = EL[i * 4 + hd];
            int s = SRC[i];
            num = fmaf(p, bf2f(hb[(size_t)s * DOUT + k]), num);
        }
        out[oi] = num / (den + EPS_F) + out[oi];
    } else {
        const float adv = ad_[(size_t)n * 4 + hd];
        float m = -3.4e38f;
        for (int i = 0; i < d; ++i) {
            float el = as_[(size_t)srcs[o + i] * 4 + hd] + adv;
            el = (el > 0.0f) ? el : NEG_SLOPE * el;
            m = fmaxf(m, el);
        }
        float num = 0.0f, den = 0.0f;
        for (int i = 0; i < d; ++i) {
            int s = srcs[o + i];
            float el = as_[(size_t)s * 4 + hd] + adv;
            el = (el > 0.0f) ? el : NEG_SLOPE * el;
            float p = __expf(el - m);
            den += p;
            num += p * bf2f(hb[(size_t)s * DOUT + k]);
        }
        out[oi] = num / (den + EPS_F) + out[oi];
    }
}

extern "C" void kernel_launch(void* const* d_in, const int* in_sizes, int n_in,
                              void* d_out, int out_size, void* d_ws, size_t ws_size,
                              hipStream_t stream) {
    const float* x   = (const float*)d_in[0];
    const float* Wp  = (const float*)d_in[1];
    const float* att = (const float*)d_in[2];
    const float* Ws  = (const float*)d_in[3];
    const int*   ei  = (const int*)d_in[4];
    float* out = (float*)d_out;

    char* ws = (char*)d_ws;
    unsigned short* hb     = (unsigned short*)(ws);              // 12.8 MB
    unsigned short* Wt     = (unsigned short*)(ws + 12800000);   // 64 KB
    float*          as_    = (float*)(ws + 12865536);            // 0.8 MB
    float*          ad_    = (float*)(ws + 13665536);            // 0.8 MB
    int*            deg    = (int*)(ws + 14465536);              // 0.2 MB
    int*            ofs    = (int*)(ws + 14665536);              // 0.2 MB
    int*            cursor = (int*)(ws + 14865536);              // 0.2 MB
    int*            srcs   = (int*)(ws + 15065536);              // 3.2 MB
    int*            flag   = (int*)(ws + 18265536);

    hipMemsetAsync(deg, 0, (size_t)N_NODES * 4, stream);

    k_detect<<<1, 256, 0, stream>>>(ei, flag);
    k_prepw<<<256, 128, 0, stream>>>(Wp, Ws, Wt);
    k_gemm<<<(N_NODES + 63) / 64, 256, 0, stream>>>(x, Wt, hb, out);
    k_attdot<<<(N_NODES * NHEAD + 255) / 256, 256, 0, stream>>>(hb, att, as_, ad_);
    k_hist<<<(E_EDGES + 255) / 256, 256, 0, stream>>>(ei, flag, deg);
    k_scan<<<1, SCAN_T, 0, stream>>>(deg, ofs, cursor);
    k_scatter<<<(E_EDGES + 255) / 256, 256, 0, stream>>>(ei, flag, cursor, srcs);
    k_gat<<<N_NODES, 128, 0, stream>>>(ofs, deg, srcs, as_, ad_, hb, out);
}

// Round 5
// 215.360 us; speedup vs baseline: 3.0943x; 1.4900x over previous
//
#include <hip/hip_runtime.h>
#include <hip/hip_bf16.h>

#define N_NODES 50000
#define E_EDGES 800000
#define NHEAD 4
#define DHEAD 32
#define DOUT 128   // NHEAD*DHEAD == D_IN
#define NEG_SLOPE 0.01f
#define EPS_F 1e-16f
#define DMAX 512

typedef __attribute__((ext_vector_type(8))) short bf16x8;
typedef __attribute__((ext_vector_type(4))) float f32x4;

__device__ __forceinline__ float bf2f(unsigned short u) {
    return __uint_as_float((unsigned)u << 16);
}
__device__ __forceinline__ unsigned short f2bf(float f) {
    return __bfloat16_as_ushort(__float2bfloat16(f));   // RNE
}

// ---- edge index fetch, robust to int32 vs int64 storage ----
__device__ __forceinline__ void load_edge(const int* __restrict__ ei, int isI64,
                                          int e, int& src, int& dst) {
    if (isI64) { src = ei[2 * e]; dst = ei[2 * (E_EDGES + e)]; }
    else       { src = ei[e];     dst = ei[E_EDGES + e]; }
}

// Detect int64-vs-int32: sample 2048 odd int32 positions; all zero => int64.
__global__ void k_detect(const int* __restrict__ ei, int* __restrict__ flag) {
    __shared__ int cnt;
    if (threadIdx.x == 0) cnt = 0;
    __syncthreads();
    int nz = 0;
    #pragma unroll
    for (int k = 0; k < 8; ++k) {
        int pos = (threadIdx.x + k * 256) * 2 + 1;
        if (ei[pos] != 0) nz = 1;
    }
    if (nz) atomicOr(&cnt, 1);
    __syncthreads();
    if (threadIdx.x == 0) *flag = (cnt == 0) ? 1 : 0;
}

// ---- K0: transpose+cvt weights: Wt[c][k] bf16, c in [0,256) over [Wp|Ws] ----
__global__ void k_prepw(const float* __restrict__ Wp, const float* __restrict__ Ws,
                        unsigned short* __restrict__ Wt) {
    int c = blockIdx.x;     // 0..255
    int k = threadIdx.x;    // 0..127
    float v = (c < DOUT) ? Wp[k * DOUT + c] : Ws[k * DOUT + (c - DOUT)];
    Wt[c * DOUT + k] = f2bf(v);
}

// ---- K1: MFMA GEMM: [hb | out] = bf16(x) @ [Wp | Ws]  (no LDS, no barriers)
__global__ __launch_bounds__(256) void k_gemm(const float* __restrict__ x,
                                              const unsigned short* __restrict__ Wt,
                                              unsigned short* __restrict__ hb,
                                              float* __restrict__ out) {
    const int wid = threadIdx.x >> 6;
    const int l   = threadIdx.x & 63;
    const int l15 = l & 15;
    const int lq  = l >> 4;             // 0..3
    const int rowbase = blockIdx.x * 64 + wid * 16;
    const int koff = lq * 8;

    int arow = rowbase + l15;
    if (arow > N_NODES - 1) arow = N_NODES - 1;
    const float* __restrict__ xr = x + (size_t)arow * DOUT;
    bf16x8 afr[4];
    #pragma unroll
    for (int ks = 0; ks < 4; ++ks) {
        float4 u0 = *(const float4*)(xr + ks * 32 + koff);
        float4 u1 = *(const float4*)(xr + ks * 32 + koff + 4);
        bf16x8 a;
        a[0] = (short)f2bf(u0.x); a[1] = (short)f2bf(u0.y);
        a[2] = (short)f2bf(u0.z); a[3] = (short)f2bf(u0.w);
        a[4] = (short)f2bf(u1.x); a[5] = (short)f2bf(u1.y);
        a[6] = (short)f2bf(u1.z); a[7] = (short)f2bf(u1.w);
        afr[ks] = a;
    }

    f32x4 acc[16];
    #pragma unroll
    for (int nf = 0; nf < 16; ++nf) acc[nf] = (f32x4)(0.0f);

    #pragma unroll
    for (int nf = 0; nf < 16; ++nf) {
        const unsigned short* wp = Wt + (size_t)(nf * 16 + l15) * DOUT + koff;
        #pragma unroll
        for (int ks = 0; ks < 4; ++ks) {
            bf16x8 b = *(const bf16x8*)(wp + ks * 32);
            acc[nf] = __builtin_amdgcn_mfma_f32_16x16x32_bf16(afr[ks], b, acc[nf], 0, 0, 0);
        }
    }

    #pragma unroll
    for (int nf = 0; nf < 16; ++nf) {
        #pragma unroll
        for (int q = 0; q < 4; ++q) {
            int row = rowbase + lq * 4 + q;
            if (row < N_NODES) {
                if (nf < 8)
                    hb[(size_t)row * DOUT + nf * 16 + l15] = f2bf(acc[nf][q]);
                else
                    out[(size_t)row * DOUT + (nf - 8) * 16 + l15] = acc[nf][q];
            }
        }
    }
}

// ---- K1b: per-node attention dots (reads bf16 hb) ----
__global__ __launch_bounds__(256) void k_attdot(const unsigned short* __restrict__ hb,
                                                const float* __restrict__ att,
                                                float* __restrict__ as_,
                                                float* __restrict__ ad_) {
    int nh = blockIdx.x * 256 + threadIdx.x;
    if (nh >= N_NODES * NHEAD) return;
    int n = nh >> 2, hd = nh & 3;
    const uint4* hv = (const uint4*)(hb + (size_t)n * DOUT + hd * DHEAD);
    const float* a1 = att + hd * 2 * DHEAD;
    const float* a2 = a1 + DHEAD;
    float s1 = 0.0f, s2 = 0.0f;
    #pragma unroll
    for (int q = 0; q < 4; ++q) {
        uint4 u = hv[q];
        unsigned vv[4] = {u.x, u.y, u.z, u.w};
        #pragma unroll
        for (int t = 0; t < 4; ++t) {
            float lo = bf2f((unsigned short)(vv[t] & 0xffff));
            float hi = bf2f((unsigned short)(vv[t] >> 16));
            int j = q * 8 + t * 2;
            s1 += lo * a1[j] + hi * a1[j + 1];
            s2 += lo * a2[j] + hi * a2[j + 1];
        }
    }
    as_[nh] = s1;
    ad_[nh] = s2;
}

// ---- K2a: histogram of dst ----
__global__ __launch_bounds__(256) void k_hist(const int* __restrict__ ei,
                                              const int* __restrict__ flag,
                                              int* __restrict__ deg) {
    int e = blockIdx.x * 256 + threadIdx.x;
    if (e >= E_EDGES) return;
    int src, dst;
    load_edge(ei, *flag, e, src, dst);
    if ((unsigned)dst >= N_NODES) return;
    atomicAdd(deg + dst, 1);
}

// ---- K2b: hierarchical exclusive scan (196 blocks of 256) ----
#define NCHUNK ((N_NODES + 255) / 256)   // 196

__global__ __launch_bounds__(256) void k_scan1(const int* __restrict__ deg,
                                               int* __restrict__ partial) {
    __shared__ int red[256];
    int t = threadIdx.x;
    int n = blockIdx.x * 256 + t;
    int v = (n < N_NODES) ? deg[n] : 0;
    red[t] = v;
    __syncthreads();
    #pragma unroll
    for (int off = 128; off; off >>= 1) {
        if (t < off) red[t] += red[t + off];
        __syncthreads();
    }
    if (t == 0) partial[blockIdx.x] = red[0];
}

__global__ __launch_bounds__(256) void k_scan2(int* __restrict__ partial,
                                               int* __restrict__ pbase) {
    __shared__ int s[256];
    int t = threadIdx.x;
    int v = (t < NCHUNK) ? partial[t] : 0;
    s[t] = v;
    __syncthreads();
    #pragma unroll
    for (int off = 1; off < 256; off <<= 1) {
        int u = (t >= off) ? s[t - off] : 0;
        __syncthreads();
        s[t] += u;
        __syncthreads();
    }
    pbase[t] = s[t] - v;   // exclusive
}

__global__ __launch_bounds__(256) void k_scan3(const int* __restrict__ deg,
                                               const int* __restrict__ pbase,
                                               int* __restrict__ ofs,
                                               int* __restrict__ cursor) {
    __shared__ int s[256];
    int t = threadIdx.x;
    int n = blockIdx.x * 256 + t;
    int v = (n < N_NODES) ? deg[n] : 0;
    s[t] = v;
    __syncthreads();
    #pragma unroll
    for (int off = 1; off < 256; off <<= 1) {
        int u = (t >= off) ? s[t - off] : 0;
        __syncthreads();
        s[t] += u;
        __syncthreads();
    }
    int ex = s[t] - v + pbase[blockIdx.x];
    if (n < N_NODES) { ofs[n] = ex; cursor[n] = ex; }
}

// ---- K2c: scatter edges into CSR order ----
__global__ __launch_bounds__(256) void k_scatter(const int* __restrict__ ei,
                                                 const int* __restrict__ flag,
                                                 int* __restrict__ cursor,
                                                 int* __restrict__ srcs) {
    int e = blockIdx.x * 256 + threadIdx.x;
    if (e >= E_EDGES) return;
    int src, dst;
    load_edge(ei, *flag, e, src, dst);
    if ((unsigned)src >= N_NODES || (unsigned)dst >= N_NODES) return;
    int pos = atomicAdd(cursor + dst, 1);
    srcs[pos] = src;
}

// ---- K3: per-node gather: el/exp once per (edge,head) in LDS, bf16 h rows ----
__global__ __launch_bounds__(128) void k_gat(const int* __restrict__ ofs,
                                             const int* __restrict__ deg,
                                             const int* __restrict__ srcs,
                                             const float* __restrict__ as_,
                                             const float* __restrict__ ad_,
                                             const unsigned short* __restrict__ hb,
                                             float* __restrict__ out) {
    __shared__ float EL[DMAX * NHEAD];   // 8 KB
    __shared__ int   SRC[DMAX];          // 2 KB

    const int n = blockIdx.x;
    const int k = threadIdx.x;
    const int hd = k >> 5;
    const int l = k & 31;
    const int o = ofs[n];
    const int d = deg[n];
    size_t oi = (size_t)n * DOUT + k;

    if (d <= DMAX) {
        for (int i = k; i < d; i += 128) SRC[i] = srcs[o + i];
        __syncthreads();
        const float4 adv4 = *(const float4*)(ad_ + (size_t)n * 4);
        const float adv_arr[4] = {adv4.x, adv4.y, adv4.z, adv4.w};
        for (int w = k; w < d * NHEAD; w += 128) {
            int e = w >> 2, hh = w & 3;
            float el = as_[(size_t)SRC[e] * 4 + hh] + adv_arr[hh];
            EL[w] = (el > 0.0f) ? el : NEG_SLOPE * el;
        }
        __syncthreads();
        float m = -3.4e38f;
        for (int i = l; i < d; i += 32) m = fmaxf(m, EL[i * 4 + hd]);
        #pragma unroll
        for (int off = 16; off; off >>= 1) m = fmaxf(m, __shfl_xor(m, off));
        float den = 0.0f;
        for (int i = l; i < d; i += 32) {
            float p = __expf(EL[i * 4 + hd] - m);
            EL[i * 4 + hd] = p;
            den += p;
        }
        #pragma unroll
        for (int off = 16; off; off >>= 1) den += __shfl_xor(den, off);
        __syncthreads();
        float num = 0.0f;
        for (int i = 0; i < d; ++i) {
            float p = EL[i * 4 + hd];
            int s = SRC[i];
            num = fmaf(p, bf2f(hb[(size_t)s * DOUT + k]), num);
        }
        out[oi] = num / (den + EPS_F) + out[oi];
    } else {
        const float adv = ad_[(size_t)n * 4 + hd];
        float m = -3.4e38f;
        for (int i = 0; i < d; ++i) {
            float el = as_[(size_t)srcs[o + i] * 4 + hd] + adv;
            el = (el > 0.0f) ? el : NEG_SLOPE * el;
            m = fmaxf(m, el);
        }
        float num = 0.0f, den = 0.0f;
        for (int i = 0; i < d; ++i) {
            int s = srcs[o + i];
            float el = as_[(size_t)s * 4 + hd] + adv;
            el = (el > 0.0f) ? el : NEG_SLOPE * el;
            float p = __expf(el - m);
            den += p;
            num += p * bf2f(hb[(size_t)s * DOUT + k]);
        }
        out[oi] = num / (den + EPS_F) + out[oi];
    }
}

extern "C" void kernel_launch(void* const* d_in, const int* in_sizes, int n_in,
                              void* d_out, int out_size, void* d_ws, size_t ws_size,
                              hipStream_t stream) {
    const float* x   = (const float*)d_in[0];
    const float* Wp  = (const float*)d_in[1];
    const float* att = (const float*)d_in[2];
    const float* Ws  = (const float*)d_in[3];
    const int*   ei  = (const int*)d_in[4];
    float* out = (float*)d_out;

    char* ws = (char*)d_ws;
    unsigned short* hb      = (unsigned short*)(ws);              // 12.8 MB
    unsigned short* Wt      = (unsigned short*)(ws + 12800000);   // 64 KB
    float*          as_     = (float*)(ws + 12865536);            // 0.8 MB
    float*          ad_     = (float*)(ws + 13665536);            // 0.8 MB
    int*            deg     = (int*)(ws + 14465536);              // 0.2 MB
    int*            ofs     = (int*)(ws + 14665536);              // 0.2 MB
    int*            cursor  = (int*)(ws + 14865536);              // 0.2 MB
    int*            srcs    = (int*)(ws + 15065536);              // 3.2 MB
    int*            partial = (int*)(ws + 18265536);              // 1 KB
    int*            pbase   = (int*)(ws + 18266560);              // 1 KB
    int*            flag    = (int*)(ws + 18267584);

    hipMemsetAsync(deg, 0, (size_t)N_NODES * 4, stream);

    k_detect<<<1, 256, 0, stream>>>(ei, flag);
    k_prepw<<<256, 128, 0, stream>>>(Wp, Ws, Wt);
    k_gemm<<<(N_NODES + 63) / 64, 256, 0, stream>>>(x, Wt, hb, out);
    k_attdot<<<(N_NODES * NHEAD + 255) / 256, 256, 0, stream>>>(hb, att, as_, ad_);
    k_hist<<<(E_EDGES + 255) / 256, 256, 0, stream>>>(ei, flag, deg);
    k_scan1<<<NCHUNK, 256, 0, stream>>>(deg, partial);
    k_scan2<<<1, 256, 0, stream>>>(partial, pbase);
    k_scan3<<<NCHUNK, 256, 0, stream>>>(deg, pbase, ofs, cursor);
    k_scatter<<<(E_EDGES + 255) / 256, 256, 0, stream>>>(ei, flag, cursor, srcs);
    k_gat<<<N_NODES, 128, 0, stream>>>(ofs, deg, srcs, as_, ad_, hb, out);
}

// Round 6
// 200.521 us; speedup vs baseline: 3.3233x; 1.0740x over previous
//
#include <hip/hip_runtime.h>
#include <hip/hip_bf16.h>

#define N_NODES 50000
#define E_EDGES 800000
#define NHEAD 4
#define DHEAD 32
#define DOUT 128   // NHEAD*DHEAD == D_IN
#define NEG_SLOPE 0.01f
#define EPS_F 1e-16f
#define DMAX 256
#define ELP 264    // EL head pitch (words); 264%32==8 -> heads hit distinct banks

typedef __attribute__((ext_vector_type(8))) short bf16x8;
typedef __attribute__((ext_vector_type(4))) float f32x4;

__device__ __forceinline__ float bf2f(unsigned short u) {
    return __uint_as_float((unsigned)u << 16);
}
__device__ __forceinline__ unsigned short f2bf(float f) {
    return __bfloat16_as_ushort(__float2bfloat16(f));   // RNE
}

// ---- edge index fetch, robust to int32 vs int64 storage ----
__device__ __forceinline__ void load_edge(const int* __restrict__ ei, int isI64,
                                          int e, int& src, int& dst) {
    if (isI64) { src = ei[2 * e]; dst = ei[2 * (E_EDGES + e)]; }
    else       { src = ei[e];     dst = ei[E_EDGES + e]; }
}

// ---- K0: weight transpose+cvt (blocks 0..255) + int64-detect (block 256) ----
__global__ __launch_bounds__(128) void k_prep(const float* __restrict__ Wp,
                                              const float* __restrict__ Ws,
                                              const int* __restrict__ ei,
                                              unsigned short* __restrict__ Wt,
                                              int* __restrict__ flag) {
    int b = blockIdx.x;
    if (b < 256) {
        int c = b, k = threadIdx.x;   // col c of [Wp|Ws], row k
        float v = (c < DOUT) ? Wp[k * DOUT + c] : Ws[k * DOUT + (c - DOUT)];
        Wt[c * DOUT + k] = f2bf(v);
    } else {
        __shared__ int cnt;
        if (threadIdx.x == 0) cnt = 0;
        __syncthreads();
        int nz = 0;
        #pragma unroll
        for (int k2 = 0; k2 < 16; ++k2) {
            int pos = (threadIdx.x + k2 * 128) * 2 + 1;   // odd int32 slots
            if (ei[pos] != 0) nz = 1;
        }
        if (nz) atomicOr(&cnt, 1);
        __syncthreads();
        if (threadIdx.x == 0) *flag = (cnt == 0) ? 1 : 0;
    }
}

// ---- K1: MFMA GEMM [hb | out] = bf16(x) @ [Wp | Ws], fused attdot epilogue ----
// 4 waves, 64 rows/block (782*64 == 50048: hb/as_/ad_ padded, out guarded).
// C/D layout: col=lane&15, row=(lane>>4)*4+reg  [learn_hip m89].
#define HBP 142    // LDS h-tile pitch in bf16 (71 words; odd -> spread banks)
__global__ __launch_bounds__(256) void k_gemm(const float* __restrict__ x,
                                              const unsigned short* __restrict__ Wt,
                                              const float* __restrict__ att,
                                              unsigned short* __restrict__ hb,
                                              float* __restrict__ as_,
                                              float* __restrict__ ad_,
                                              float* __restrict__ out) {
    __shared__ unsigned short HB[64 * HBP];   // 18.2 KB
    const int tid = threadIdx.x;
    const int wid = tid >> 6;
    const int l   = tid & 63;
    const int l15 = l & 15;
    const int lq  = l >> 4;
    const int rowbase = blockIdx.x * 64 + wid * 16;
    const int koff = lq * 8;

    int arow = rowbase + l15;
    if (arow > N_NODES - 1) arow = N_NODES - 1;
    const float* __restrict__ xr = x + (size_t)arow * DOUT;
    bf16x8 afr[4];
    #pragma unroll
    for (int ks = 0; ks < 4; ++ks) {
        float4 u0 = *(const float4*)(xr + ks * 32 + koff);
        float4 u1 = *(const float4*)(xr + ks * 32 + koff + 4);
        bf16x8 a;
        a[0] = (short)f2bf(u0.x); a[1] = (short)f2bf(u0.y);
        a[2] = (short)f2bf(u0.z); a[3] = (short)f2bf(u0.w);
        a[4] = (short)f2bf(u1.x); a[5] = (short)f2bf(u1.y);
        a[6] = (short)f2bf(u1.z); a[7] = (short)f2bf(u1.w);
        afr[ks] = a;
    }

    f32x4 acc[16];
    #pragma unroll
    for (int nf = 0; nf < 16; ++nf) acc[nf] = (f32x4)(0.0f);

    #pragma unroll
    for (int nf = 0; nf < 16; ++nf) {
        const unsigned short* wp = Wt + (size_t)(nf * 16 + l15) * DOUT + koff;
        #pragma unroll
        for (int ks = 0; ks < 4; ++ks) {
            bf16x8 b = *(const bf16x8*)(wp + ks * 32);
            acc[nf] = __builtin_amdgcn_mfma_f32_16x16x32_bf16(afr[ks], b, acc[nf], 0, 0, 0);
        }
    }

    // skip half -> out (d_out is exactly N_NODES rows: guard)
    #pragma unroll
    for (int nf = 8; nf < 16; ++nf) {
        #pragma unroll
        for (int q = 0; q < 4; ++q) {
            int row = rowbase + lq * 4 + q;
            if (row < N_NODES)
                out[(size_t)row * DOUT + (nf - 8) * 16 + l15] = acc[nf][q];
        }
    }
    // h half -> LDS tile (bf16)
    #pragma unroll
    for (int nf = 0; nf < 8; ++nf) {
        #pragma unroll
        for (int q = 0; q < 4; ++q) {
            int rl = wid * 16 + lq * 4 + q;
            HB[rl * HBP + nf * 16 + l15] = f2bf(acc[nf][q]);
        }
    }
    __syncthreads();

    // fused attdot: 256 threads = 64 rows x 4 heads
    {
        int rl = tid >> 2, hd = tid & 3;
        const unsigned* HBu = (const unsigned*)HB;
        const float* a1 = att + hd * 2 * DHEAD;
        const float* a2 = a1 + DHEAD;
        float s1 = 0.0f, s2 = 0.0f;
        #pragma unroll
        for (int j = 0; j < 16; ++j) {
            unsigned u = HBu[rl * (HBP / 2) + hd * 16 + j];
            float lo = bf2f((unsigned short)(u & 0xffff));
            float hi = bf2f((unsigned short)(u >> 16));
            s1 += lo * a1[2 * j] + hi * a1[2 * j + 1];
            s2 += lo * a2[2 * j] + hi * a2[2 * j + 1];
        }
        int rowg = blockIdx.x * 64 + rl;     // as_/ad_ padded to 50048
        as_[(size_t)rowg * 4 + hd] = s1;
        ad_[(size_t)rowg * 4 + hd] = s2;
    }

    // hb global store, 16B per lane (hb padded to 50048 rows)
    {
        const unsigned* HBu = (const unsigned*)HB;
        #pragma unroll
        for (int it = 0; it < 4; ++it) {
            int idx = it * 256 + tid;        // 0..1023
            int row = idx >> 4, g = idx & 15;
            int wb = row * (HBP / 2) + g * 4;
            uint4 v;
            v.x = HBu[wb]; v.y = HBu[wb + 1]; v.z = HBu[wb + 2]; v.w = HBu[wb + 3];
            *(uint4*)(hb + ((size_t)(blockIdx.x * 64 + row)) * DOUT + g * 8) = v;
        }
    }
}

// ---- K2a: histogram of dst ----
__global__ __launch_bounds__(256) void k_hist(const int* __restrict__ ei,
                                              const int* __restrict__ flag,
                                              int* __restrict__ deg) {
    int e = blockIdx.x * 256 + threadIdx.x;
    if (e >= E_EDGES) return;
    int src, dst;
    load_edge(ei, *flag, e, src, dst);
    if ((unsigned)dst >= N_NODES) return;
    atomicAdd(deg + dst, 1);
}

// ---- K2b: hierarchical exclusive scan (196 blocks of 256) ----
#define NCHUNK ((N_NODES + 255) / 256)   // 196

__global__ __launch_bounds__(256) void k_scan1(const int* __restrict__ deg,
                                               int* __restrict__ partial) {
    __shared__ int red[256];
    int t = threadIdx.x;
    int n = blockIdx.x * 256 + t;
    int v = (n < N_NODES) ? deg[n] : 0;
    red[t] = v;
    __syncthreads();
    #pragma unroll
    for (int off = 128; off; off >>= 1) {
        if (t < off) red[t] += red[t + off];
        __syncthreads();
    }
    if (t == 0) partial[blockIdx.x] = red[0];
}

__global__ __launch_bounds__(256) void k_scan2(int* __restrict__ partial,
                                               int* __restrict__ pbase) {
    __shared__ int s[256];
    int t = threadIdx.x;
    int v = (t < NCHUNK) ? partial[t] : 0;
    s[t] = v;
    __syncthreads();
    #pragma unroll
    for (int off = 1; off < 256; off <<= 1) {
        int u = (t >= off) ? s[t - off] : 0;
        __syncthreads();
        s[t] += u;
        __syncthreads();
    }
    pbase[t] = s[t] - v;   // exclusive
}

__global__ __launch_bounds__(256) void k_scan3(const int* __restrict__ deg,
                                               const int* __restrict__ pbase,
                                               int* __restrict__ ofs,
                                               int* __restrict__ cursor) {
    __shared__ int s[256];
    int t = threadIdx.x;
    int n = blockIdx.x * 256 + t;
    int v = (n < N_NODES) ? deg[n] : 0;
    s[t] = v;
    __syncthreads();
    #pragma unroll
    for (int off = 1; off < 256; off <<= 1) {
        int u = (t >= off) ? s[t - off] : 0;
        __syncthreads();
        s[t] += u;
        __syncthreads();
    }
    int ex = s[t] - v + pbase[blockIdx.x];
    if (n < N_NODES) { ofs[n] = ex; cursor[n] = ex; }
}

// ---- K2c: scatter edges into CSR order ----
__global__ __launch_bounds__(256) void k_scatter(const int* __restrict__ ei,
                                                 const int* __restrict__ flag,
                                                 int* __restrict__ cursor,
                                                 int* __restrict__ srcs) {
    int e = blockIdx.x * 256 + threadIdx.x;
    if (e >= E_EDGES) return;
    int src, dst;
    load_edge(ei, *flag, e, src, dst);
    if ((unsigned)src >= N_NODES || (unsigned)dst >= N_NODES) return;
    int pos = atomicAdd(cursor + dst, 1);
    srcs[pos] = src;
}

// ---- K3: per-node gather v3: 2 nodes/block, 64 thr/node, uint col-pair loads ----
// Thread k of a node owns cols {2k, 2k+1}; head hd=k>>4 (both cols same head).
__global__ __launch_bounds__(128) void k_gat(const int* __restrict__ ofs,
                                             const int* __restrict__ deg,
                                             const int* __restrict__ srcs,
                                             const float* __restrict__ as_,
                                             const float* __restrict__ ad_,
                                             const unsigned short* __restrict__ hb,
                                             float* __restrict__ out) {
    __shared__ float EL[2][NHEAD * ELP];   // 2 x 4.2 KB
    __shared__ int   SRC[2][DMAX];         // 2 x 1 KB

    const int sub = threadIdx.x >> 6;      // node slot in block
    const int k   = threadIdx.x & 63;
    const int hd  = k >> 4;
    const int l16 = k & 15;
    const int n = blockIdx.x * 2 + sub;    // 25000*2 == 50000 exactly
    const int o = ofs[n];
    const int d = deg[n];
    const unsigned* __restrict__ hbu = (const unsigned*)hb;
    float* ELn = EL[sub];
    int*   SRCn = SRC[sub];

    int fast = __syncthreads_and(d <= DMAX);   // block-uniform branch

    if (fast) {
        // phase AB: stage srcs + el for all 4 heads (one float4 gather per edge)
        const float4 adv4 = *(const float4*)(ad_ + (size_t)n * 4);
        for (int e = k; e < d; e += 64) {
            int s = srcs[o + e];
            SRCn[e] = s;
            float4 a4 = *(const float4*)(as_ + (size_t)s * 4);
            float e0 = a4.x + adv4.x, e1 = a4.y + adv4.y;
            float e2 = a4.z + adv4.z, e3 = a4.w + adv4.w;
            ELn[0 * ELP + e] = (e0 > 0.0f) ? e0 : NEG_SLOPE * e0;
            ELn[1 * ELP + e] = (e1 > 0.0f) ? e1 : NEG_SLOPE * e1;
            ELn[2 * ELP + e] = (e2 > 0.0f) ? e2 : NEG_SLOPE * e2;
            ELn[3 * ELP + e] = (e3 > 0.0f) ? e3 : NEG_SLOPE * e3;
        }
        __syncthreads();
        // phase C: per-head max (16-lane groups), exp in place, denom
        float m = -3.4e38f;
        for (int i = l16; i < d; i += 16) m = fmaxf(m, ELn[hd * ELP + i]);
        #pragma unroll
        for (int off = 8; off; off >>= 1) m = fmaxf(m, __shfl_xor(m, off));
        float den = 0.0f;
        for (int i = l16; i < d; i += 16) {
            float p = __expf(ELn[hd * ELP + i] - m);
            ELn[hd * ELP + i] = p;
            den += p;
        }
        #pragma unroll
        for (int off = 8; off; off >>= 1) den += __shfl_xor(den, off);
        __syncthreads();
        // phase D: weighted gather, one uint (2 bf16 cols) per edge per lane
        float num0 = 0.0f, num1 = 0.0f;
        for (int i = 0; i < d; ++i) {
            float p = ELn[hd * ELP + i];
            int s = SRCn[i];
            unsigned u = hbu[(size_t)s * (DOUT / 2) + k];
            num0 = fmaf(p, bf2f((unsigned short)(u & 0xffff)), num0);
            num1 = fmaf(p, bf2f((unsigned short)(u >> 16)), num1);
        }
        float inv = 1.0f / (den + EPS_F);
        float2* op = (float2*)(out + (size_t)n * DOUT + 2 * k);
        float2 sk = *op;
        *op = make_float2(num0 * inv + sk.x, num1 * inv + sk.y);
    } else {
        // fallback (any node in block with degree > DMAX): no LDS, no syncs
        const float adv = ad_[(size_t)n * 4 + hd];
        float m = -3.4e38f;
        for (int i = 0; i < d; ++i) {
            float el = as_[(size_t)srcs[o + i] * 4 + hd] + adv;
            el = (el > 0.0f) ? el : NEG_SLOPE * el;
            m = fmaxf(m, el);
        }
        float den = 0.0f, num0 = 0.0f, num1 = 0.0f;
        for (int i = 0; i < d; ++i) {
            int s = srcs[o + i];
            float el = as_[(size_t)s * 4 + hd] + adv;
            el = (el > 0.0f) ? el : NEG_SLOPE * el;
            float p = __expf(el - m);
            den += p;
            unsigned u = hbu[(size_t)s * (DOUT / 2) + k];
            num0 = fmaf(p, bf2f((unsigned short)(u & 0xffff)), num0);
            num1 = fmaf(p, bf2f((unsigned short)(u >> 16)), num1);
        }
        float inv = 1.0f / (den + EPS_F);
        float2* op = (float2*)(out + (size_t)n * DOUT + 2 * k);
        float2 sk = *op;
        *op = make_float2(num0 * inv + sk.x, num1 * inv + sk.y);
    }
}

extern "C" void kernel_launch(void* const* d_in, const int* in_sizes, int n_in,
                              void* d_out, int out_size, void* d_ws, size_t ws_size,
                              hipStream_t stream) {
    const float* x   = (const float*)d_in[0];
    const float* Wp  = (const float*)d_in[1];
    const float* att = (const float*)d_in[2];
    const float* Ws  = (const float*)d_in[3];
    const int*   ei  = (const int*)d_in[4];
    float* out = (float*)d_out;

    char* ws = (char*)d_ws;
    // padded row count 50048 = 782*64 for guard-free gemm stores
    unsigned short* hb      = (unsigned short*)(ws);               // 12,812,288 B
    unsigned short* Wt      = (unsigned short*)(ws + 12812288);    // 65,536 B
    float*          as_     = (float*)(ws + 12877824);             // 800,768 B
    float*          ad_     = (float*)(ws + 13678592);             // 800,768 B
    int*            deg     = (int*)(ws + 14479360);               // 200,000 B
    int*            ofs     = (int*)(ws + 14679360);               // 200,000 B
    int*            cursor  = (int*)(ws + 14879360);               // 200,000 B
    int*            srcs    = (int*)(ws + 15079360);               // 3,200,000 B
    int*            partial = (int*)(ws + 18279360);               // 1,024 B
    int*            pbase   = (int*)(ws + 18280384);               // 1,024 B
    int*            flag    = (int*)(ws + 18281408);

    hipMemsetAsync(deg, 0, (size_t)N_NODES * 4, stream);

    k_prep<<<257, 128, 0, stream>>>(Wp, Ws, ei, Wt, flag);
    k_gemm<<<(N_NODES + 63) / 64, 256, 0, stream>>>(x, Wt, att, hb, as_, ad_, out);
    k_hist<<<(E_EDGES + 255) / 256, 256, 0, stream>>>(ei, flag, deg);
    k_scan1<<<NCHUNK, 256, 0, stream>>>(deg, partial);
    k_scan2<<<1, 256, 0, stream>>>(partial, pbase);
    k_scan3<<<NCHUNK, 256, 0, stream>>>(deg, pbase, ofs, cursor);
    k_scatter<<<(E_EDGES + 255) / 256, 256, 0, stream>>>(ei, flag, cursor, srcs);
    k_gat<<<N_NODES / 2, 128, 0, stream>>>(ofs, deg, srcs, as_, ad_, hb, out);
}

// Round 7
// 132.026 us; speedup vs baseline: 5.0475x; 1.5188x over previous
//
#include <hip/hip_runtime.h>
#include <hip/hip_bf16.h>

#define N_NODES 50000
#define E_EDGES 800000
#define NHEAD 4
#define DHEAD 32
#define DOUT 128   // NHEAD*DHEAD == D_IN
#define NEG_SLOPE 0.01f
#define EPS_F 1e-16f
#define DMAX 256
#define ELP 264    // EL head pitch (words); 264%32==8 -> heads hit distinct banks
#define NB 196     // dst buckets of 256 nodes (dst>>8), 49999>>8 == 195
#define CAP 8192   // payload capacity per bucket (mean 4096, sigma 64)

typedef __attribute__((ext_vector_type(8))) short bf16x8;
typedef __attribute__((ext_vector_type(4))) float f32x4;

__device__ __forceinline__ float bf2f(unsigned short u) {
    return __uint_as_float((unsigned)u << 16);
}
__device__ __forceinline__ unsigned short f2bf(float f) {
    return __bfloat16_as_ushort(__float2bfloat16(f));   // RNE
}

// ---- edge index fetch, robust to int32 vs int64 storage ----
__device__ __forceinline__ void load_edge(const int* __restrict__ ei, int isI64,
                                          int e, int& src, int& dst) {
    if (isI64) { src = ei[2 * e]; dst = ei[2 * (E_EDGES + e)]; }
    else       { src = ei[e];     dst = ei[E_EDGES + e]; }
}

// ---- K0: weight transpose+cvt (blocks 0..255) + int64-detect (block 256) ----
__global__ __launch_bounds__(128) void k_prep(const float* __restrict__ Wp,
                                              const float* __restrict__ Ws,
                                              const int* __restrict__ ei,
                                              unsigned short* __restrict__ Wt,
                                              int* __restrict__ flag) {
    int b = blockIdx.x;
    if (b < 256) {
        int c = b, k = threadIdx.x;   // col c of [Wp|Ws], row k
        float v = (c < DOUT) ? Wp[k * DOUT + c] : Ws[k * DOUT + (c - DOUT)];
        Wt[c * DOUT + k] = f2bf(v);
    } else {
        __shared__ int cnt;
        if (threadIdx.x == 0) cnt = 0;
        __syncthreads();
        int nz = 0;
        #pragma unroll
        for (int k2 = 0; k2 < 16; ++k2) {
            int pos = (threadIdx.x + k2 * 128) * 2 + 1;   // odd int32 slots
            if (ei[pos] != 0) nz = 1;
        }
        if (nz) atomicOr(&cnt, 1);
        __syncthreads();
        if (threadIdx.x == 0) *flag = (cnt == 0) ? 1 : 0;
    }
}

// ---- K1: MFMA GEMM [hb | out] = bf16(x) @ [Wp | Ws], fused attdot epilogue ----
// 4 waves, 64 rows/block (782*64 == 50048: hb/as_/ad_ padded, out guarded).
// C/D layout: col=lane&15, row=(lane>>4)*4+reg  [learn_hip m89].
#define HBP 142    // LDS h-tile pitch in bf16
__global__ __launch_bounds__(256) void k_gemm(const float* __restrict__ x,
                                              const unsigned short* __restrict__ Wt,
                                              const float* __restrict__ att,
                                              unsigned short* __restrict__ hb,
                                              float* __restrict__ as_,
                                              float* __restrict__ ad_,
                                              float* __restrict__ out) {
    __shared__ unsigned short HB[64 * HBP];   // 18.2 KB
    const int tid = threadIdx.x;
    const int wid = tid >> 6;
    const int l   = tid & 63;
    const int l15 = l & 15;
    const int lq  = l >> 4;
    const int rowbase = blockIdx.x * 64 + wid * 16;
    const int koff = lq * 8;

    int arow = rowbase + l15;
    if (arow > N_NODES - 1) arow = N_NODES - 1;
    const float* __restrict__ xr = x + (size_t)arow * DOUT;
    bf16x8 afr[4];
    #pragma unroll
    for (int ks = 0; ks < 4; ++ks) {
        float4 u0 = *(const float4*)(xr + ks * 32 + koff);
        float4 u1 = *(const float4*)(xr + ks * 32 + koff + 4);
        bf16x8 a;
        a[0] = (short)f2bf(u0.x); a[1] = (short)f2bf(u0.y);
        a[2] = (short)f2bf(u0.z); a[3] = (short)f2bf(u0.w);
        a[4] = (short)f2bf(u1.x); a[5] = (short)f2bf(u1.y);
        a[6] = (short)f2bf(u1.z); a[7] = (short)f2bf(u1.w);
        afr[ks] = a;
    }

    f32x4 acc[16];
    #pragma unroll
    for (int nf = 0; nf < 16; ++nf) acc[nf] = (f32x4)(0.0f);

    #pragma unroll
    for (int nf = 0; nf < 16; ++nf) {
        const unsigned short* wp = Wt + (size_t)(nf * 16 + l15) * DOUT + koff;
        #pragma unroll
        for (int ks = 0; ks < 4; ++ks) {
            bf16x8 b = *(const bf16x8*)(wp + ks * 32);
            acc[nf] = __builtin_amdgcn_mfma_f32_16x16x32_bf16(afr[ks], b, acc[nf], 0, 0, 0);
        }
    }

    // skip half -> out (d_out is exactly N_NODES rows: guard)
    #pragma unroll
    for (int nf = 8; nf < 16; ++nf) {
        #pragma unroll
        for (int q = 0; q < 4; ++q) {
            int row = rowbase + lq * 4 + q;
            if (row < N_NODES)
                out[(size_t)row * DOUT + (nf - 8) * 16 + l15] = acc[nf][q];
        }
    }
    // h half -> LDS tile (bf16)
    #pragma unroll
    for (int nf = 0; nf < 8; ++nf) {
        #pragma unroll
        for (int q = 0; q < 4; ++q) {
            int rl = wid * 16 + lq * 4 + q;
            HB[rl * HBP + nf * 16 + l15] = f2bf(acc[nf][q]);
        }
    }
    __syncthreads();

    // fused attdot: 256 threads = 64 rows x 4 heads
    {
        int rl = tid >> 2, hd = tid & 3;
        const unsigned* HBu = (const unsigned*)HB;
        const float* a1 = att + hd * 2 * DHEAD;
        const float* a2 = a1 + DHEAD;
        float s1 = 0.0f, s2 = 0.0f;
        #pragma unroll
        for (int j = 0; j < 16; ++j) {
            unsigned u = HBu[rl * (HBP / 2) + hd * 16 + j];
            float lo = bf2f((unsigned short)(u & 0xffff));
            float hi = bf2f((unsigned short)(u >> 16));
            s1 += lo * a1[2 * j] + hi * a1[2 * j + 1];
            s2 += lo * a2[2 * j] + hi * a2[2 * j + 1];
        }
        int rowg = blockIdx.x * 64 + rl;     // as_/ad_ padded to 50048
        as_[(size_t)rowg * 4 + hd] = s1;
        ad_[(size_t)rowg * 4 + hd] = s2;
    }

    // hb global store, 16B per lane (hb padded to 50048 rows)
    {
        const unsigned* HBu = (const unsigned*)HB;
        #pragma unroll
        for (int it = 0; it < 4; ++it) {
            int idx = it * 256 + tid;        // 0..1023
            int row = idx >> 4, g = idx & 15;
            int wb = row * (HBP / 2) + g * 4;
            uint4 v;
            v.x = HBu[wb]; v.y = HBu[wb + 1]; v.z = HBu[wb + 2]; v.w = HBu[wb + 3];
            *(uint4*)(hb + ((size_t)(blockIdx.x * 64 + row)) * DOUT + g * 8) = v;
        }
    }
}

// ---- K2a: bucket partition. 256 blocks x 3125 edges. Payload (dl<<16)|src. ----
__global__ __launch_bounds__(256) void k_part(const int* __restrict__ ei,
                                              const int* __restrict__ flag,
                                              int* __restrict__ bucketCnt,
                                              unsigned* __restrict__ payload) {
    __shared__ int hist[NB];
    __shared__ int curs[NB];
    const int t = threadIdx.x;
    const int base = blockIdx.x * 3125;
    const int isI64 = *flag;

    for (int i = t; i < NB; i += 256) hist[i] = 0;
    __syncthreads();
    for (int i = t; i < 3125; i += 256) {
        int src, dst;
        load_edge(ei, isI64, base + i, src, dst);
        if ((unsigned)dst < N_NODES) atomicAdd(&hist[dst >> 8], 1);
    }
    __syncthreads();
    for (int i = t; i < NB; i += 256)
        curs[i] = atomicAdd(&bucketCnt[i], hist[i]);
    __syncthreads();
    for (int i = t; i < 3125; i += 256) {
        int src, dst;
        load_edge(ei, isI64, base + i, src, dst);
        if ((unsigned)src >= N_NODES || (unsigned)dst >= N_NODES) continue;
        int b = dst >> 8;
        int pos = atomicAdd(&curs[b], 1);
        if (pos < CAP)
            payload[((size_t)b << 13) + pos] = ((unsigned)(dst & 255) << 16) | (unsigned)src;
    }
}

// ---- K2b: per-bucket CSR build: deg/ofs (bucket-based) + srcs scatter ----
// One block per bucket; all scatter writes confined to this bucket's region.
__global__ __launch_bounds__(256) void k_csr(const int* __restrict__ bucketCnt,
                                             const unsigned* __restrict__ payload,
                                             int* __restrict__ deg,
                                             int* __restrict__ ofs,
                                             int* __restrict__ srcs) {
    __shared__ int h[256];
    __shared__ int cur[256];
    __shared__ int sc[256];
    const int b = blockIdx.x;
    const int t = threadIdx.x;
    int cnt = bucketCnt[b];
    if (cnt > CAP) cnt = CAP;
    const unsigned* __restrict__ pl = payload + ((size_t)b << 13);

    h[t] = 0;
    __syncthreads();
    for (int i = t; i < cnt; i += 256) atomicAdd(&h[pl[i] >> 16], 1);
    __syncthreads();
    int v = h[t];
    sc[t] = v;
    __syncthreads();
    #pragma unroll
    for (int off = 1; off < 256; off <<= 1) {
        int u = (t >= off) ? sc[t - off] : 0;
        __syncthreads();
        sc[t] += u;
        __syncthreads();
    }
    int ex = sc[t] - v;              // exclusive local prefix
    cur[t] = ex;
    int n = (b << 8) + t;
    if (n < N_NODES) { deg[n] = v; ofs[n] = (b << 13) + ex; }
    __syncthreads();
    for (int i = t; i < cnt; i += 256) {
        unsigned p = pl[i];
        int pos = atomicAdd(&cur[p >> 16], 1);
        srcs[((size_t)b << 13) + pos] = (int)(p & 0xFFFFu);
    }
}

// ---- K3: per-node gather: 2 nodes/block, 64 thr/node, uint col-pair loads ----
__global__ __launch_bounds__(128) void k_gat(const int* __restrict__ ofs,
                                             const int* __restrict__ deg,
                                             const int* __restrict__ srcs,
                                             const float* __restrict__ as_,
                                             const float* __restrict__ ad_,
                                             const unsigned short* __restrict__ hb,
                                             float* __restrict__ out) {
    __shared__ float EL[2][NHEAD * ELP];   // 2 x 4.2 KB
    __shared__ int   SRC[2][DMAX];         // 2 x 1 KB

    const int sub = threadIdx.x >> 6;      // node slot in block
    const int k   = threadIdx.x & 63;
    const int hd  = k >> 4;
    const int l16 = k & 15;
    const int n = blockIdx.x * 2 + sub;    // 25000*2 == 50000 exactly
    const int o = ofs[n];
    const int d = deg[n];
    const unsigned* __restrict__ hbu = (const unsigned*)hb;
    float* ELn = EL[sub];
    int*   SRCn = SRC[sub];

    int fast = __syncthreads_and(d <= DMAX);   // block-uniform branch

    if (fast) {
        const float4 adv4 = *(const float4*)(ad_ + (size_t)n * 4);
        for (int e = k; e < d; e += 64) {
            int s = srcs[o + e];
            SRCn[e] = s;
            float4 a4 = *(const float4*)(as_ + (size_t)s * 4);
            float e0 = a4.x + adv4.x, e1 = a4.y + adv4.y;
            float e2 = a4.z + adv4.z, e3 = a4.w + adv4.w;
            ELn[0 * ELP + e] = (e0 > 0.0f) ? e0 : NEG_SLOPE * e0;
            ELn[1 * ELP + e] = (e1 > 0.0f) ? e1 : NEG_SLOPE * e1;
            ELn[2 * ELP + e] = (e2 > 0.0f) ? e2 : NEG_SLOPE * e2;
            ELn[3 * ELP + e] = (e3 > 0.0f) ? e3 : NEG_SLOPE * e3;
        }
        __syncthreads();
        float m = -3.4e38f;
        for (int i = l16; i < d; i += 16) m = fmaxf(m, ELn[hd * ELP + i]);
        #pragma unroll
        for (int off = 8; off; off >>= 1) m = fmaxf(m, __shfl_xor(m, off));
        float den = 0.0f;
        for (int i = l16; i < d; i += 16) {
            float p = __expf(ELn[hd * ELP + i] - m);
            ELn[hd * ELP + i] = p;
            den += p;
        }
        #pragma unroll
        for (int off = 8; off; off >>= 1) den += __shfl_xor(den, off);
        __syncthreads();
        float num0 = 0.0f, num1 = 0.0f;
        for (int i = 0; i < d; ++i) {
            float p = ELn[hd * ELP + i];
            int s = SRCn[i];
            unsigned u = hbu[(size_t)s * (DOUT / 2) + k];
            num0 = fmaf(p, bf2f((unsigned short)(u & 0xffff)), num0);
            num1 = fmaf(p, bf2f((unsigned short)(u >> 16)), num1);
        }
        float inv = 1.0f / (den + EPS_F);
        float2* op = (float2*)(out + (size_t)n * DOUT + 2 * k);
        float2 sk = *op;
        *op = make_float2(num0 * inv + sk.x, num1 * inv + sk.y);
    } else {
        const float adv = ad_[(size_t)n * 4 + hd];
        float m = -3.4e38f;
        for (int i = 0; i < d; ++i) {
            float el = as_[(size_t)srcs[o + i] * 4 + hd] + adv;
            el = (el > 0.0f) ? el : NEG_SLOPE * el;
            m = fmaxf(m, el);
        }
        float den = 0.0f, num0 = 0.0f, num1 = 0.0f;
        for (int i = 0; i < d; ++i) {
            int s = srcs[o + i];
            float el = as_[(size_t)s * 4 + hd] + adv;
            el = (el > 0.0f) ? el : NEG_SLOPE * el;
            float p = __expf(el - m);
            den += p;
            unsigned u = hbu[(size_t)s * (DOUT / 2) + k];
            num0 = fmaf(p, bf2f((unsigned short)(u & 0xffff)), num0);
            num1 = fmaf(p, bf2f((unsigned short)(u >> 16)), num1);
        }
        float inv = 1.0f / (den + EPS_F);
        float2* op = (float2*)(out + (size_t)n * DOUT + 2 * k);
        float2 sk = *op;
        *op = make_float2(num0 * inv + sk.x, num1 * inv + sk.y);
    }
}

extern "C" void kernel_launch(void* const* d_in, const int* in_sizes, int n_in,
                              void* d_out, int out_size, void* d_ws, size_t ws_size,
                              hipStream_t stream) {
    const float* x   = (const float*)d_in[0];
    const float* Wp  = (const float*)d_in[1];
    const float* att = (const float*)d_in[2];
    const float* Ws  = (const float*)d_in[3];
    const int*   ei  = (const int*)d_in[4];
    float* out = (float*)d_out;

    char* ws = (char*)d_ws;
    unsigned short* hb        = (unsigned short*)(ws);              // 12,812,288 B (50048 rows)
    unsigned short* Wt        = (unsigned short*)(ws + 12812288);   // 65,536 B
    float*          as_       = (float*)(ws + 12877824);            // 800,768 B
    float*          ad_       = (float*)(ws + 13678592);            // 800,768 B
    int*            deg       = (int*)(ws + 14479360);              // 200,704 B
    int*            ofs       = (int*)(ws + 14680064);              // 200,704 B
    unsigned*       payload   = (unsigned*)(ws + 14880768);         // 6,422,528 B
    int*            srcs      = (int*)(ws + 21303296);              // 6,422,528 B
    int*            bucketCnt = (int*)(ws + 27725824);              // 1,024 B
    int*            flag      = (int*)(ws + 27726848);

    hipMemsetAsync(bucketCnt, 0, NB * 4, stream);

    k_prep<<<257, 128, 0, stream>>>(Wp, Ws, ei, Wt, flag);
    k_gemm<<<(N_NODES + 63) / 64, 256, 0, stream>>>(x, Wt, att, hb, as_, ad_, out);
    k_part<<<256, 256, 0, stream>>>(ei, flag, bucketCnt, payload);
    k_csr<<<NB, 256, 0, stream>>>(bucketCnt, payload, deg, ofs, srcs);
    k_gat<<<N_NODES / 2, 128, 0, stream>>>(ofs, deg, srcs, as_, ad_, hb, out);
}